// Round 1
// baseline (1223.499 us; speedup 1.0000x reference)
//
#include <hip/hip_runtime.h>
#include <math.h>

#define HIDDEN 128
#define NSTEP  64
#define BATCH2 4096
#define EPB    8      // evals per block
#define OUTD   100

__device__ __forceinline__ float fast_tanh(float z) {
    // tanh(z) = 1 - 2/(exp(2z)+1); exact limits at +/-inf, ~2 ulp in between
    float e = __expf(2.0f * z);
    return 1.0f - 2.0f / (e + 1.0f);
}

// Zero the u accumulator region and write u0 directly (runs before eval_kernel
// on the same stream; avoids memset nodes and d_ws entirely for output init).
__global__ __launch_bounds__(256) void init_kernel(
    const float* __restrict__ samples_s, float* __restrict__ out)
{
    int b = blockIdx.x * blockDim.x + threadIdx.x;
    if (b < BATCH2) {
        out[b] = 0.0f;
        float s0 = samples_s[b * (NSTEP + 1)];
        // sqrt(beta/(2*pi))/out_dim = sqrt(1e6/6.283185307)/100 = 3.9894228040
        out[BATCH2 + b] = 3.9894228040143267f * expf(-500000.0f * s0 * s0);
    }
}

__global__ __launch_bounds__(128) void eval_kernel(
    const float* __restrict__ W1, const float* __restrict__ b1,
    const float* __restrict__ W2, const float* __restrict__ b2,
    const float* __restrict__ W3, const float* __restrict__ b3,
    const float* __restrict__ W4, const float* __restrict__ b4,
    const int*   __restrict__ samples_n,
    const float* __restrict__ samples_s,
    const float* __restrict__ samples_dB,
    const float* __restrict__ tptr,
    float* __restrict__ out)
{
    // Activations: [tangent(0=val,1=d1,2=d2)][eval][hidden]
    __shared__ float A[3][EPB][HIDDEN];
    __shared__ float sS[EPB], sTk[EPB], sDb[EPB];
    __shared__ int   sN[EPB];
    __shared__ float red[2][3][EPB];

    const int tid = threadIdx.x;
    const int e0  = blockIdx.x * EPB;        // global eval base
    const float t  = tptr[0];
    const float dt = t / (float)NSTEP;

    if (tid < EPB) {
        int ge = e0 + tid;
        int b  = ge >> 6;                    // sample
        int j  = ge & 63;                    // eval index 0..63
        int c  = NSTEP - j;                  // s/n column = 64 - j
        sS[tid]  = samples_s[b * (NSTEP + 1) + c];
        sN[tid]  = samples_n[b * (NSTEP + 1) + c];
        sDb[tid] = samples_dB[b * NSTEP + (NSTEP - 1 - j)];
        sTk[tid] = (j == 0) ? t : t - dt * (float)(j - 1);
    }
    __syncthreads();

    // ---- layer 1: x=[s,tk], dx/ds=[1,0] ----
    {
        float w1a = W1[tid];                 // W1[0][k]
        float w1b = W1[HIDDEN + tid];        // W1[1][k]
        float bb  = b1[tid];
        #pragma unroll
        for (int e = 0; e < EPB; ++e) {
            float z  = fmaf(w1a, sS[e], fmaf(w1b, sTk[e], bb));
            float zd = w1a;                  // z'' = 0
            float a  = fast_tanh(z);
            float g  = 1.0f - a * a;
            float ad = g * zd;
            float add = -2.0f * a * ad * zd; // g*zdd - 2*a*ad*zd with zdd=0
            A[0][e][tid] = a; A[1][e][tid] = ad; A[2][e][tid] = add;
        }
    }
    __syncthreads();

    // ---- layers 2 and 3: z_k = b[k] + sum_j A[.][e][j] * W[j][k] ----
    for (int layer = 0; layer < 2; ++layer) {
        const float* __restrict__ W    = layer ? W3 : W2;
        const float* __restrict__ bias = layer ? b3 : b2;
        float acc[3][EPB];
        #pragma unroll
        for (int tp = 0; tp < 3; ++tp)
            #pragma unroll
            for (int e = 0; e < EPB; ++e) acc[tp][e] = 0.0f;

        const float* Wp = W + tid;
        for (int j = 0; j < HIDDEN; j += 4) {
            float w0 = Wp[(j + 0) * HIDDEN];
            float w1 = Wp[(j + 1) * HIDDEN];
            float w2 = Wp[(j + 2) * HIDDEN];
            float w3 = Wp[(j + 3) * HIDDEN];
            #pragma unroll
            for (int e = 0; e < EPB; ++e) {
                #pragma unroll
                for (int tp = 0; tp < 3; ++tp) {
                    // wave-uniform address -> LDS broadcast (conflict-free)
                    const float4 v = *(const float4*)&A[tp][e][j];
                    float a = acc[tp][e];
                    a = fmaf(w0, v.x, a);
                    a = fmaf(w1, v.y, a);
                    a = fmaf(w2, v.z, a);
                    a = fmaf(w3, v.w, a);
                    acc[tp][e] = a;
                }
            }
        }
        float bk = bias[tid];
        __syncthreads();   // all reads of A done before overwrite
        #pragma unroll
        for (int e = 0; e < EPB; ++e) {
            float z = acc[0][e] + bk, zd = acc[1][e], zdd = acc[2][e];
            float a  = fast_tanh(z);
            float g  = 1.0f - a * a;
            float ad = g * zd;
            float add = fmaf(g, zdd, -2.0f * a * ad * zd);
            A[0][e][tid] = a; A[1][e][tid] = ad; A[2][e][tid] = add;
        }
        __syncthreads();
    }

    // ---- layer 4: dot with W4[:, n_e] (thread = element index) ----
    float p[3][EPB];
    #pragma unroll
    for (int e = 0; e < EPB; ++e) {
        float w = W4[tid * OUTD + sN[e]];
        p[0][e] = A[0][e][tid] * w;
        p[1][e] = A[1][e][tid] * w;
        p[2][e] = A[2][e][tid] * w;
    }
    // 64-lane butterfly reduce
    #pragma unroll
    for (int off = 32; off >= 1; off >>= 1)
        #pragma unroll
        for (int tp = 0; tp < 3; ++tp)
            #pragma unroll
            for (int e = 0; e < EPB; ++e)
                p[tp][e] += __shfl_xor(p[tp][e], off, 64);

    int wave = tid >> 6;
    if ((tid & 63) == 0) {
        #pragma unroll
        for (int tp = 0; tp < 3; ++tp)
            #pragma unroll
            for (int e = 0; e < EPB; ++e)
                red[wave][tp][e] = p[tp][e];
    }
    __syncthreads();

    if (tid < EPB) {
        int e  = tid;
        int ge = e0 + e;
        int b  = ge >> 6;
        int j  = ge & 63;
        float u   = red[0][0][e] + red[1][0][e] + b4[sN[e]];
        float ps  = red[0][1][e] + red[1][1][e];
        float pss = red[0][2][e] + red[1][2][e];
        float contrib = -(ps * sDb[e] + pss * dt * 0.5f);
        if (j == 0) contrib += u;   // eval j=0 supplies the initial u
        atomicAdd(&out[b], contrib);
    }
}

extern "C" void kernel_launch(void* const* d_in, const int* in_sizes, int n_in,
                              void* d_out, int out_size, void* d_ws, size_t ws_size,
                              hipStream_t stream) {
    const float* W1 = (const float*)d_in[0];
    const float* b1 = (const float*)d_in[1];
    const float* W2 = (const float*)d_in[2];
    const float* b2 = (const float*)d_in[3];
    const float* W3 = (const float*)d_in[4];
    const float* b3 = (const float*)d_in[5];
    const float* W4 = (const float*)d_in[6];
    const float* b4 = (const float*)d_in[7];
    const int*   sn  = (const int*)d_in[8];
    const float* ss  = (const float*)d_in[9];
    const float* sdB = (const float*)d_in[10];
    const float* t   = (const float*)d_in[11];
    float* out = (float*)d_out;

    init_kernel<<<(BATCH2 + 255) / 256, 256, 0, stream>>>(ss, out);
    eval_kernel<<<(BATCH2 * NSTEP) / EPB, 128, 0, stream>>>(
        W1, b1, W2, b2, W3, b3, W4, b4, sn, ss, sdB, t, out);
}

// Round 2
// 244.076 us; speedup vs baseline: 5.0128x; 5.0128x over previous
//
#include <hip/hip_runtime.h>
#include <math.h>

#define HIDDEN 128
#define NSTEP  64
#define BATCH2 4096
#define OUTD   100
#define E      16     // evals per block
#define LDA    136    // padded A-row length in shorts (272 B: 2-way bank alias = free)

typedef __attribute__((ext_vector_type(8))) short  short8;
typedef __attribute__((ext_vector_type(4))) float  f32x4;

static __device__ __forceinline__ short f2bf(float f) {
    unsigned u = __float_as_uint(f);
    u += 0x7fff + ((u >> 16) & 1);          // round-to-nearest-even
    return (short)(u >> 16);
}
static __device__ __forceinline__ float bf2f(short s) {
    return __uint_as_float(((unsigned)(unsigned short)s) << 16);
}
static __device__ __forceinline__ float fast_tanh(float z) {
    float e = __expf(2.0f * z);
    return 1.0f - 2.0f / (e + 1.0f);
}

// out[0..4095] = 0 (u accumulator), out[4096..8191] = u0 closed form.
__global__ __launch_bounds__(256) void init_kernel(
    const float* __restrict__ samples_s, float* __restrict__ out)
{
    int b = blockIdx.x * blockDim.x + threadIdx.x;
    if (b < BATCH2) {
        out[b] = 0.0f;
        float s0 = samples_s[b * (NSTEP + 1)];
        out[BATCH2 + b] = 3.9894228040143267f * expf(-500000.0f * s0 * s0);
    }
}

// d_ws: [0..16383] = W2T bf16 (WT[n*128+k] = W2[k][n]), [16384..32767] = W3T bf16.
__global__ __launch_bounds__(256) void prep_weights(
    const float* __restrict__ W2, const float* __restrict__ W3,
    short* __restrict__ wbf)
{
    int t = blockIdx.x * blockDim.x + threadIdx.x;   // 0..32767
    int m = t >> 14;
    int r = t & 16383;
    int n = r >> 7;
    int k = r & 127;
    const float* W = m ? W3 : W2;
    wbf[t] = f2bf(W[k * HIDDEN + n]);
}

__global__ __launch_bounds__(256) void eval_kernel(
    const float* __restrict__ W1, const float* __restrict__ b1,
    const float* __restrict__ b2, const float* __restrict__ b3,
    const float* __restrict__ W4, const float* __restrict__ b4,
    const short* __restrict__ wbf,
    const int*   __restrict__ samples_n,
    const float* __restrict__ samples_s,
    const float* __restrict__ samples_dB,
    const float* __restrict__ tptr,
    float* __restrict__ out)
{
    // A matrix: 48 rows (tile0=value e0..15, tile1=d1, tile2=d2) x 128 cols, bf16
    __shared__ short Abuf[48 * LDA];
    __shared__ float sS[E], sTk[E], sDb[E];
    __shared__ int   sNn[E];
    __shared__ float sContrib[E];

    const int tid = threadIdx.x;
    const float t  = tptr[0];
    const float dt = t / (float)NSTEP;
    const int e0 = blockIdx.x * E;

    if (tid < E) {
        int ge = e0 + tid;
        int b = ge >> 6, j = ge & 63, c = NSTEP - j;
        sS[tid]  = samples_s[b * (NSTEP + 1) + c];
        sNn[tid] = samples_n[b * (NSTEP + 1) + c];
        sDb[tid] = samples_dB[b * NSTEP + (NSTEP - 1 - j)];
        sTk[tid] = (j == 0) ? t : t - dt * (float)(j - 1);
    }
    __syncthreads();

    // ---- layer 1 (elementwise): 2048 (e,h) pairs, 8 per thread ----
    {
        int h = tid & 127;
        float w1a = W1[h], w1b = W1[HIDDEN + h], bb = b1[h];
        #pragma unroll
        for (int i = 0; i < 8; ++i) {
            int e = i * 2 + (tid >> 7);
            float z  = fmaf(w1a, sS[e], fmaf(w1b, sTk[e], bb));
            float a  = fast_tanh(z);
            float g  = 1.0f - a * a;
            float ad = g * w1a;                 // z' = w1a, z'' = 0
            float add = -2.0f * a * ad * w1a;
            Abuf[e * LDA + h]        = f2bf(a);
            Abuf[(16 + e) * LDA + h] = f2bf(ad);
            Abuf[(32 + e) * LDA + h] = f2bf(add);
        }
    }
    __syncthreads();

    const int lane = tid & 63;
    const int wv   = tid >> 6;     // wave 0..3, owns col-tiles 2wv, 2wv+1
    const int quad = lane >> 4;
    const int m16  = lane & 15;

    // ---- layers 2 and 3: MFMA ----
    #pragma unroll
    for (int layer = 0; layer < 2; ++layer) {
        const short* __restrict__ WTl  = wbf + layer * (HIDDEN * HIDDEN);
        const float* __restrict__ bias = layer ? b3 : b2;

        f32x4 acc[2][3];
        #pragma unroll
        for (int ct = 0; ct < 2; ++ct)
            #pragma unroll
            for (int tp = 0; tp < 3; ++tp)
                acc[ct][tp] = (f32x4){0.f, 0.f, 0.f, 0.f};

        #pragma unroll
        for (int kk = 0; kk < 4; ++kk) {
            const int k0 = kk * 32 + quad * 8;
            short8 af[3];
            #pragma unroll
            for (int rt = 0; rt < 3; ++rt)
                af[rt] = *(const short8*)&Abuf[(rt * 16 + m16) * LDA + k0];
            short8 bfr[2];
            #pragma unroll
            for (int ct = 0; ct < 2; ++ct) {
                int n = (wv * 2 + ct) * 16 + m16;
                bfr[ct] = *(const short8*)&WTl[n * HIDDEN + k0];
            }
            #pragma unroll
            for (int ct = 0; ct < 2; ++ct)
                #pragma unroll
                for (int tp = 0; tp < 3; ++tp)
                    acc[ct][tp] = __builtin_amdgcn_mfma_f32_16x16x32_bf16(
                        af[tp], bfr[ct], acc[ct][tp], 0, 0, 0);
        }
        __syncthreads();   // all Abuf reads done before overwrite

        #pragma unroll
        for (int ct = 0; ct < 2; ++ct) {
            int h = (wv * 2 + ct) * 16 + m16;
            float bcol = bias[h];
            #pragma unroll
            for (int r = 0; r < 4; ++r) {
                int e = quad * 4 + r;         // C layout: row = quad*4+reg
                float zv  = acc[ct][0][r] + bcol;
                float zd  = acc[ct][1][r];
                float zdd = acc[ct][2][r];
                float a  = fast_tanh(zv);
                float g  = 1.0f - a * a;
                float ad = g * zd;
                float add = fmaf(g, zdd, -2.0f * a * ad * zd);
                Abuf[e * LDA + h]        = f2bf(a);
                Abuf[(16 + e) * LDA + h] = f2bf(ad);
                Abuf[(32 + e) * LDA + h] = f2bf(add);
            }
        }
        __syncthreads();
    }

    // ---- layer 4: per-eval dot with W4[:, n_e], 16 lanes per eval ----
    {
        int e = tid >> 4, sub = tid & 15;
        int n = sNn[e];
        float sv = 0.f, sd = 0.f, sdd = 0.f;
        #pragma unroll
        for (int i = 0; i < 8; ++i) {
            int h = sub + 16 * i;
            float w = W4[h * OUTD + n];
            sv  = fmaf(bf2f(Abuf[e * LDA + h]),        w, sv);
            sd  = fmaf(bf2f(Abuf[(16 + e) * LDA + h]), w, sd);
            sdd = fmaf(bf2f(Abuf[(32 + e) * LDA + h]), w, sdd);
        }
        #pragma unroll
        for (int off = 8; off >= 1; off >>= 1) {
            sv  += __shfl_xor(sv,  off, 16);
            sd  += __shfl_xor(sd,  off, 16);
            sdd += __shfl_xor(sdd, off, 16);
        }
        if (sub == 0) {
            int ge = e0 + e, j = ge & 63;
            float u = sv + b4[n];
            float c = -(sd * sDb[e] + sdd * dt * 0.5f);
            if (j == 0) c += u;
            sContrib[e] = c;
        }
    }
    __syncthreads();

    if (tid == 0) {
        float tot = 0.f;
        #pragma unroll
        for (int e = 0; e < E; ++e) tot += sContrib[e];
        atomicAdd(&out[e0 >> 6], tot);    // all 16 evals share sample b
    }
}

extern "C" void kernel_launch(void* const* d_in, const int* in_sizes, int n_in,
                              void* d_out, int out_size, void* d_ws, size_t ws_size,
                              hipStream_t stream) {
    const float* W1 = (const float*)d_in[0];
    const float* b1 = (const float*)d_in[1];
    const float* W2 = (const float*)d_in[2];
    const float* b2 = (const float*)d_in[3];
    const float* W3 = (const float*)d_in[4];
    const float* b3 = (const float*)d_in[5];
    const float* W4 = (const float*)d_in[6];
    const float* b4 = (const float*)d_in[7];
    const int*   sn  = (const int*)d_in[8];
    const float* ss  = (const float*)d_in[9];
    const float* sdB = (const float*)d_in[10];
    const float* t   = (const float*)d_in[11];
    float* out = (float*)d_out;
    short* wbf = (short*)d_ws;          // 64 KB: W2T, W3T in bf16

    init_kernel<<<(BATCH2 + 255) / 256, 256, 0, stream>>>(ss, out);
    prep_weights<<<(2 * HIDDEN * HIDDEN) / 256, 256, 0, stream>>>(W2, W3, wbf);
    eval_kernel<<<(BATCH2 * NSTEP) / E, 256, 0, stream>>>(
        W1, b1, b2, b3, W4, b4, wbf, sn, ss, sdB, t, out);
}